// Round 9
// baseline (590.207 us; speedup 1.0000x reference)
//
#include <hip/hip_runtime.h>
#include <hip/hip_cooperative_groups.h>
#include <math.h>

namespace cg = cooperative_groups;

#define MM    2048
#define CC    64
#define NIF   461
#define INS   512
#define EPSN  1e-6f

typedef unsigned long long u64;

// ws float offsets
#define OFF_P     ((size_t)0)          // 256 x 512
#define OFF_ITF   ((size_t)131072)     // 256 x 464
#define OFF_ALLOC ((size_t)249856)     // 256 x 2048
#define OFF_MRW   ((size_t)774144)     // 256 x 2048
#define OFF_SUMS  ((size_t)1298432)    // 256 x 16: [0]=wsum,[1..4]=h,[5..8]=g
#define OFF_SCAL  ((size_t)1302528)    // 256 x 2048 x 16
#define OFF_W8    ((size_t)9691136)    // 256 x 2048 x 8

__device__ __forceinline__ float actfn(int c, float g){
  if (c < 256)  return tanhf(g);
  if (c < 260)  return fmaxf(g,0.f) + log1pf(expf(-fabsf(g)));
  if (c < 324)  return tanhf(g);
  if (c == 324) return fmaxf(g,0.f) + log1pf(expf(-fabsf(g)));
  if (c < 389)  return 1.f/(1.f+expf(-g));
  if (c < 453)  return tanhf(g);
  if (c < 457)  return 1.f/(1.f+expf(-g));
  if (c < 460)  return g;
  return 1.f/(1.f+expf(-g));
}

__global__ __launch_bounds__(256,2) void dnc_all(
    const float* __restrict__ xi, const float* __restrict__ W,
    const float* __restrict__ gamma, const float* __restrict__ beta,
    const float* __restrict__ memory, const float* __restrict__ read_w,
    const float* __restrict__ write_w, const float* __restrict__ usage,
    float* __restrict__ ws, float* __restrict__ out)
{
  cg::grid_group grid = cg::this_grid();
  const int bid = blockIdx.x, tid = threadIdx.x;
  const int lane = tid & 63, wvid = tid >> 6;   // 4 waves
  const int b = bid & 255, half = bid >> 8;     // 4 slices: half*4 .. half*4+3

  __shared__ __align__(16) unsigned char sMem[19456];
  __shared__ float sR[64];
  u64*   keysL = (u64*)sMem;                  // [2048] 16KB      (P1)
  float* sTL   = (float*)(sMem + 16384);      // [260]            (P1)
  float* sactL = (float*)(sMem + 17424);      // [464]            (P1)
  float* sxiL  = (float*)sMem;                // [512]            (P0)
  float* sW8   = (float*)sMem;                // [2048] 8KB       (P4)
  float* ldsP  = (float*)(sMem + 8192);       // [2048] 8KB       (P4)

  // ================= Phase 0: zero out/sums + itf GEMM chunk ===============
  if (tid < 128) out[((size_t)bid<<7) + tid] = 0.f;
  if (bid < 256 && tid < 16) ws[OFF_SUMS + (size_t)bid*16 + tid] = 0.f;
  sxiL[tid]     = xi[(size_t)b*INS + tid];
  sxiL[tid+256] = xi[(size_t)b*INS + tid + 256];
  __syncthreads();
  {
    const float4 x0 = ((const float4*)sxiL)[lane*2];
    const float4 x1 = ((const float4*)sxiL)[lane*2+1];
    const int cbase = half*232;
    const int cend  = (cbase+232 < NIF) ? cbase+232 : NIF;
    for (int col = cbase + wvid; col < cend; col += 4) {
      const float4* Wr = (const float4*)(W + (size_t)col*INS);
      float4 a0 = Wr[lane*2], a1 = Wr[lane*2+1];
      float p = a0.x*x0.x + a0.y*x0.y + a0.z*x0.z + a0.w*x0.w
              + a1.x*x1.x + a1.y*x1.y + a1.z*x1.z + a1.w*x1.w;
      #pragma unroll
      for (int off=1; off<64; off<<=1) p += __shfl_xor(p, off);
      if (lane==0) ws[OFF_ITF + (size_t)b*464 + col] = p;
    }
  }
  __threadfence();
  grid.sync();

  // ================= Phase 1 (blocks 0..255): gates + sort + alloc =========
  if (bid < 256) {
    const float* itf = ws + OFF_ITF + (size_t)b*464;
    float v1 = (tid < NIF) ? itf[tid] : 0.f;
    float v2 = (tid+256 < NIF) ? itf[tid+256] : 0.f;
    float s = v1+v2, q = v1*v1+v2*v2;
    #pragma unroll
    for (int off=1; off<64; off<<=1){ s += __shfl_xor(s,off); q += __shfl_xor(q,off); }
    if (lane==0){ sR[wvid]=s; sR[8+wvid]=q; }
    __syncthreads();
    if (tid==0){
      float ts=sR[0]+sR[1]+sR[2]+sR[3], tq=sR[8]+sR[9]+sR[10]+sR[11];
      float mean = ts/(float)NIF;
      float var  = tq/(float)NIF - mean*mean;
      sR[16]=mean; sR[17]=rsqrtf(var+1e-5f);
    }
    __syncthreads();
    float mean=sR[16], rstd=sR[17];
    if (tid < NIF)     sactL[tid]     = actfn(tid,     (v1-mean)*rstd*gamma[tid]    +beta[tid]);
    if (tid+256 < NIF) sactL[tid+256] = actfn(tid+256, (v2-mean)*rstd*gamma[tid+256]+beta[tid+256]);
    __syncthreads();

    float* P = ws + OFF_P + (size_t)b*512;
    {
      float t0 = sactL[wvid*64 + lane];
      float qq = t0*t0;
      #pragma unroll
      for (int off=1; off<64; off<<=1) qq += __shfl_xor(qq,off);
      float fk = t0 * (sactL[256+wvid]/(sqrtf(qq)+EPSN));
      P[wvid*64+lane] = fk;
      float kk = fk * sactL[389+lane];
      #pragma unroll
      for (int off=1; off<64; off<<=1) kk += __shfl_xor(kk,off);
      if (lane==0) P[452+wvid] = kk;
    }
    if (wvid==0) {
      float t0 = sactL[260+lane];
      float qq = t0*t0;
      #pragma unroll
      for (int off=1; off<64; off<<=1) qq += __shfl_xor(qq,off);
      P[256+lane] = t0 * (sactL[324]/(sqrtf(qq)+EPSN));
      float wvv = sactL[389+lane];
      float ff = wvv*wvv;
      #pragma unroll
      for (int off=1; off<64; off<<=1) ff += __shfl_xor(ff,off);
      if (lane==0) P[456]=ff;
    } else if (wvid==1) {
      P[320+lane] = sactL[325+lane];
    } else if (wvid==2) {
      P[384+lane] = sactL[389+lane];
    } else if (wvid==3 && lane==0) {
      float a0=sactL[457], a1=sactL[458], a2=sactL[459];
      float mx = fmaxf(a0, fmaxf(a1,a2));
      float e0=expf(a0-mx), e1=expf(a1-mx), e2=expf(a2-mx);
      float is = 1.f/(e0+e1+e2);
      P[448]=e0*is; P[449]=e1*is; P[450]=e2*is; P[451]=sactL[460];
    }
    // u2 + mrw + sort keys
    {
      const float4* us4 = (const float4*)(usage   + (size_t)b*MM);
      const float4* wr4 = (const float4*)(write_w + (size_t)b*MM);
      const float4* rw4 = (const float4*)(read_w  + (size_t)b*4*MM);
      const float fg0=sactL[453], fg1=sactL[454], fg2=sactL[455], fg3=sactL[456];
      #pragma unroll
      for (int k=0;k<2;k++){
        int i4 = tid + k*256;
        float4 u = us4[i4], w2 = wr4[i4];
        float4 r0 = rw4[i4], r1 = rw4[512+i4], r2 = rw4[1024+i4], r3 = rw4[1536+i4];
        float4 mr;
        mr.x = 0.25f*(r0.x+r1.x+r2.x+r3.x);
        mr.y = 0.25f*(r0.y+r1.y+r2.y+r3.y);
        mr.z = 0.25f*(r0.z+r1.z+r2.z+r3.z);
        mr.w = 0.25f*(r0.w+r1.w+r2.w+r3.w);
        ((float4*)(ws + OFF_MRW + (size_t)b*MM))[i4] = mr;
        #define U2C(comp, off)                                                   \
        { float uu  = u.comp + (1.f-u.comp)*w2.comp;                             \
          float psi = (1.f-fg0*r0.comp)*(1.f-fg1*r1.comp)*(1.f-fg2*r2.comp)*(1.f-fg3*r3.comp); \
          float u2v = 1e-6f + (1.f-1e-6f)*(uu*psi);                              \
          keysL[i4*4+off] = ((u64)__float_as_uint(u2v)<<32) | (unsigned)(i4*4+off); }
        U2C(x,0) U2C(y,1) U2C(z,2) U2C(w,3)
        #undef U2C
      }
    }
    __syncthreads();
    for (int k2 = 2; k2 <= MM; k2 <<= 1) {
      for (int j = k2 >> 1; j > 0; j >>= 1) {
        #pragma unroll 4
        for (int c = tid; c < MM/2; c += 256) {
          int i   = ((c & ~(j-1)) << 1) | (c & (j-1));
          int ixj = i | j;
          u64 a = keysL[i], d = keysL[ixj];
          bool up = ((i & k2) == 0);
          if ((a > d) == up) { keysL[i] = d; keysL[ixj] = a; }
        }
        __syncthreads();
      }
    }
    float p8[8];
    {
      float run = 1.f;
      #pragma unroll
      for (int e=0;e<8;++e){
        float su = __uint_as_float((unsigned)(keysL[tid*8+e]>>32));
        run *= su; p8[e] = run;
      }
      sTL[tid] = run;
    }
    __syncthreads();
    float vv = sTL[tid], incl = vv;
    #pragma unroll
    for (int off=1; off<64; off<<=1) {
      float n = __shfl_up(incl, off);
      if (lane >= off) incl *= n;
    }
    float excl = __shfl_up(incl, 1);
    if (lane == 0) excl = 1.f;
    if (lane == 63) sTL[256 + wvid] = incl;
    __syncthreads();
    float base = 1.f;
    for (int w2i = 0; w2i < wvid; ++w2i) base *= sTL[256 + w2i];
    float Ex = base * excl;
    float* allocp = ws + OFF_ALLOC + (size_t)b*MM;
    #pragma unroll
    for (int e=0;e<8;++e){
      u64 kk = keysL[tid*8+e];
      float su = __uint_as_float((unsigned)(kk>>32));
      unsigned idx = (unsigned)(kk & 0xFFFFFFFFu);
      float cp = Ex * (e ? p8[e-1] : 1.f);
      allocp[idx] = (1.f - su) * cp;
    }
  }
  __threadfence();
  grid.sync();

  // ================= Phase 2: per-row scalars -> global, Σexp(write) =======
  {
    const float* P = ws + OFF_P + (size_t)b*512;
    const int q = tid & 7, rowg = tid >> 3;
    const float4 wkA = ((const float4*)(P+256))[q*2], wkB = ((const float4*)(P+256))[q*2+1];
    const float4 eA  = ((const float4*)(P+320))[q*2], eB  = ((const float4*)(P+320))[q*2+1];
    const float4 wvA = ((const float4*)(P+384))[q*2], wvB = ((const float4*)(P+384))[q*2+1];
    const float4 k0A = ((const float4*)P)[      q*2], k0B = ((const float4*)P)[      q*2+1];
    const float4 k1A = ((const float4*)P)[ 16 + q*2], k1B = ((const float4*)P)[ 16 + q*2+1];
    const float4 k2A = ((const float4*)P)[ 32 + q*2], k2B = ((const float4*)P)[ 32 + q*2+1];
    const float4 k3A = ((const float4*)P)[ 48 + q*2], k3B = ((const float4*)P)[ 48 + q*2+1];
    const float4* mem4 = (const float4*)(memory + (size_t)b*MM*CC);
    float4* scal4 = (float4*)(ws + OFF_SCAL) + (size_t)b*2048*4;
    float ewsum = 0.f;
    for (int si=0; si<4; ++si) {
      const int s = half*4 + si;
      for (int it=0; it<8; ++it) {
        int m = it*32 + rowg;
        int mg = s*256 + m;
        float4 vA = mem4[mg*16 + q*2], vB = mem4[mg*16 + q*2+1];
        float4 veA, veB;
        veA.x=vA.x*eA.x; veA.y=vA.y*eA.y; veA.z=vA.z*eA.z; veA.w=vA.w*eA.w;
        veB.x=vB.x*eB.x; veB.y=vB.y*eB.y; veB.z=vB.z*eB.z; veB.w=vB.w*eB.w;
        #define DOT(a,c) (a.x*c.x + a.y*c.y + a.z*c.z + a.w*c.w)
        float S  = DOT(vA,wkA) + DOT(vB,wkB);
        float A  = DOT(vA,vA)  + DOT(vB,vB);
        float B  = DOT(veA,vA) + DOT(veB,vB);
        float C  = DOT(veA,veA)+ DOT(veB,veB);
        float D  = DOT(vA,wvA) + DOT(vB,wvB);
        float E  = DOT(veA,wvA)+ DOT(veB,wvB);
        float G0 = DOT(vA,k0A) + DOT(vB,k0B);
        float G1 = DOT(vA,k1A) + DOT(vB,k1B);
        float G2 = DOT(vA,k2A) + DOT(vB,k2B);
        float G3 = DOT(vA,k3A) + DOT(vB,k3B);
        float H0 = DOT(veA,k0A)+ DOT(veB,k0B);
        float H1 = DOT(veA,k1A)+ DOT(veB,k1B);
        float H2 = DOT(veA,k2A)+ DOT(veB,k2B);
        float H3 = DOT(veA,k3A)+ DOT(veB,k3B);
        #undef DOT
        #pragma unroll
        for (int off=1; off<8; off<<=1) {
          S += __shfl_xor(S,off);   A += __shfl_xor(A,off);
          B += __shfl_xor(B,off);   C += __shfl_xor(C,off);
          D += __shfl_xor(D,off);   E += __shfl_xor(E,off);
          G0 += __shfl_xor(G0,off); G1 += __shfl_xor(G1,off);
          G2 += __shfl_xor(G2,off); G3 += __shfl_xor(G3,off);
          H0 += __shfl_xor(H0,off); H1 += __shfl_xor(H1,off);
          H2 += __shfl_xor(H2,off); H3 += __shfl_xor(H3,off);
        }
        if (q == 0) {
          float ew = expf(S / (sqrtf(A)+EPSN));
          ewsum += ew;
          float4 o0; o0.x=S;  o0.y=A;  o0.z=B;  o0.w=C;
          float4 o1; o1.x=D;  o1.y=E;  o1.z=ew; o1.w=0.f;
          float4 o2; o2.x=G0; o2.y=G1; o2.z=G2; o2.w=G3;
          float4 o3; o3.x=H0; o3.y=H1; o3.z=H2; o3.w=H3;
          scal4[mg*4+0]=o0; scal4[mg*4+1]=o1; scal4[mg*4+2]=o2; scal4[mg*4+3]=o3;
        }
      }
    }
    #pragma unroll
    for (int off=1; off<64; off<<=1) ewsum += __shfl_xor(ewsum,off);
    __syncthreads();
    if (lane==0) sR[wvid] = ewsum;
    __syncthreads();
    if (tid==0) atomicAdd(&ws[OFF_SUMS + (size_t)b*16], sR[0]+sR[1]+sR[2]+sR[3]);
  }
  __threadfence();
  grid.sync();

  // ================= Phase 3: weights -> w8 + h/g atomics ==================
  {
    const float* P = ws + OFF_P + (size_t)b*512;
    const float ag0=P[448], ag1=P[449], ag2=P[450], wg=P[451];
    const float K0=P[452], K1=P[453], K2v=P[454], K3v=P[455], F=P[456];
    const float invW = 1.f / ws[OFF_SUMS + (size_t)b*16];
    float h[4]={0,0,0,0}, g[4]={0,0,0,0};
    for (int si=0; si<4; ++si) {
      const int r = (half*4+si)*256 + tid;
      const float4* row = (const float4*)(ws + OFF_SCAL) + ((size_t)b*2048 + r)*4;
      float4 s0=row[0], s1=row[1], sG=row[2], sH=row[3];
      float al = ws[OFF_ALLOC + (size_t)b*MM + r];
      float mr = ws[OFF_MRW   + (size_t)b*MM + r];
      float wwv = wg*(ag0*mr + ag1*al + ag2*s1.z*invW);
      float nsq = s0.y + 2.f*wwv*(s1.x - s0.z) + wwv*wwv*(s0.w - 2.f*s1.y + F);
      float rstd = 1.f/(sqrtf(fmaxf(nsq,0.f))+EPSN);
      float e0 = expf((sG.x + wwv*(K0 -sH.x))*rstd);
      float e1 = expf((sG.y + wwv*(K1 -sH.y))*rstd);
      float e2 = expf((sG.z + wwv*(K2v-sH.z))*rstd);
      float e3 = expf((sG.w + wwv*(K3v-sH.w))*rstd);
      float4 oa; oa.x=e0; oa.y=e1; oa.z=e2; oa.w=e3;
      float4 og; og.x=e0*wwv; og.y=e1*wwv; og.z=e2*wwv; og.w=e3*wwv;
      float4* w84 = (float4*)(ws + OFF_W8) + ((size_t)b*2048 + r)*2;
      w84[0]=oa; w84[1]=og;
      h[0]+=e0; h[1]+=e1; h[2]+=e2; h[3]+=e3;
      g[0]+=og.x; g[1]+=og.y; g[2]+=og.z; g[3]+=og.w;
    }
    #pragma unroll
    for (int off=1; off<64; off<<=1) {
      #pragma unroll
      for (int r2=0;r2<4;++r2){ h[r2]+=__shfl_xor(h[r2],off); g[r2]+=__shfl_xor(g[r2],off); }
    }
    __syncthreads();
    if (lane==0){
      #pragma unroll
      for (int r2=0;r2<4;++r2){ sR[wvid*8+r2]=h[r2]; sR[wvid*8+4+r2]=g[r2]; }
    }
    __syncthreads();
    if (tid < 8){
      float ssum = sR[tid] + sR[8+tid] + sR[16+tid] + sR[24+tid];
      atomicAdd(&ws[OFF_SUMS + (size_t)b*16 + 1 + tid], ssum);
    }
  }
  __threadfence();
  grid.sync();

  // ================= Phase 4: weighted reduction + output ==================
  {
    const float* P = ws + OFF_P + (size_t)b*512;
    const float i0 = 1.f/ws[OFF_SUMS+(size_t)b*16+1];
    const float i1 = 1.f/ws[OFF_SUMS+(size_t)b*16+2];
    const float i2 = 1.f/ws[OFF_SUMS+(size_t)b*16+3];
    const float i3 = 1.f/ws[OFF_SUMS+(size_t)b*16+4];
    const float cr0 = ws[OFF_SUMS+(size_t)b*16+5]*i0;
    const float cr1 = ws[OFF_SUMS+(size_t)b*16+6]*i1;
    const float cr2 = ws[OFF_SUMS+(size_t)b*16+7]*i2;
    const float cr3 = ws[OFF_SUMS+(size_t)b*16+8]*i3;
    const int rq = lane >> 4, cq = lane & 15;
    const float4* mem4 = (const float4*)(memory + (size_t)b*MM*CC);
    for (int si=0; si<4; ++si) {
      const int s = half*4 + si;
      {
        const float4* g8 = (const float4*)(ws + OFF_W8) + ((size_t)b*2048 + s*256)*2;
        ((float4*)sW8)[tid]     = g8[tid];
        ((float4*)sW8)[tid+256] = g8[tid+256];
      }
      __syncthreads();
      float4 acc[8];
      #pragma unroll
      for (int j=0;j<8;++j){ acc[j].x=0;acc[j].y=0;acc[j].z=0;acc[j].w=0; }
      #pragma unroll 4
      for (int i=0;i<16;++i){
        int m = wvid*64 + i*4 + rq;
        float4 v = mem4[(s*256+m)*16 + cq];
        float4 wa = *(const float4*)&sW8[m*8];
        float4 wb = *(const float4*)&sW8[m*8+4];
        #define ACC(j, sc) { acc[j].x += (sc)*v.x; acc[j].y += (sc)*v.y; acc[j].z += (sc)*v.z; acc[j].w += (sc)*v.w; }
        ACC(0, wa.x) ACC(1, wa.y) ACC(2, wa.z) ACC(3, wa.w)
        ACC(4, wb.x) ACC(5, wb.y) ACC(6, wb.z) ACC(7, wb.w)
        #undef ACC
      }
      #pragma unroll
      for (int j=0;j<8;++j){
        #pragma unroll
        for (int off=16; off<64; off<<=1) {
          acc[j].x += __shfl_xor(acc[j].x, off);
          acc[j].y += __shfl_xor(acc[j].y, off);
          acc[j].z += __shfl_xor(acc[j].z, off);
          acc[j].w += __shfl_xor(acc[j].w, off);
        }
      }
      if (rq == 0) {
        float4* p4 = (float4*)&ldsP[(wvid*16 + cq)*32];
        #pragma unroll
        for (int j=0;j<8;++j) p4[j] = acc[j];
      }
      __syncthreads();
      {
        int jj = tid >> 6, c = tid & 63;
        int cq2 = c >> 2, ci = c & 3;
        float s1 = 0.f, s2 = 0.f;
        #pragma unroll
        for (int g4=0; g4<4; ++g4) {
          s1 += ldsP[(g4*16 + cq2)*32 +  jj   *4 + ci];
          s2 += ldsP[(g4*16 + cq2)*32 + (jj+4)*4 + ci];
        }
        float ir  = (jj==0)?i0:((jj==1)?i1:((jj==2)?i2:i3));
        float crr = (jj==0)?cr0:((jj==1)?cr1:((jj==2)?cr2:cr3));
        float val = ir*(s1 - P[320+c]*s2);
        if (bid < 256 && si == 0) val += crr * P[384+c];
        atomicAdd(&out[((size_t)b<<8) + tid], val);
      }
      __syncthreads();
    }
  }
}

extern "C" void kernel_launch(void* const* d_in, const int* in_sizes, int n_in,
                              void* d_out, int out_size, void* d_ws, size_t ws_size,
                              hipStream_t stream) {
  const float* xi      = (const float*)d_in[0];
  const float* W       = (const float*)d_in[1];
  const float* gamma   = (const float*)d_in[2];
  const float* beta    = (const float*)d_in[3];
  const float* memory  = (const float*)d_in[4];
  const float* read_w  = (const float*)d_in[5];
  const float* write_w = (const float*)d_in[6];
  const float* usage   = (const float*)d_in[7];
  float* ws  = (float*)d_ws;
  float* out = (float*)d_out;

  void* args[] = { (void*)&xi, (void*)&W, (void*)&gamma, (void*)&beta,
                   (void*)&memory, (void*)&read_w, (void*)&write_w, (void*)&usage,
                   (void*)&ws, (void*)&out };
  hipLaunchCooperativeKernel((const void*)dnc_all, dim3(512), dim3(256),
                             args, 0, stream);
}